// Round 2
// baseline (175.607 us; speedup 1.0000x reference)
//
#include <hip/hip_runtime.h>
#include <math.h>

#define IMG_H 4096
#define IMG_W 4096
#define ROWS_PER_THREAD 8

// One thread = 4 cols x 8 rows. Rows stream through registers (u/c/d), so the
// vertical 3-row overlap is register-reused instead of re-fetched from HBM
// across blocks on different XCDs (per-XCD L2s don't share).
__global__ __launch_bounds__(256) void nms_kernel(const float* __restrict__ img,
                                                  const float* __restrict__ theta,
                                                  float* __restrict__ out) {
    const int tid = blockIdx.x * blockDim.x + threadIdx.x;
    const int g  = tid >> 10;            // row-group (8 rows each); 1024 quad-cols per group
    const int qc = tid & 1023;
    const int y4 = qc << 2;              // starting column of the 4-px chunk
    const int x0 = g * ROWS_PER_THREAD;  // first output row of this thread

    const int yl = (y4 > 0)         ? y4 - 1 : 0;         // clamped; col-border outputs are 0
    const int yr = (y4 + 4 < IMG_W) ? y4 + 4 : IMG_W - 1;

    // load a row's 4-px chunk + the two shifted edge scalars
    auto load_row = [&](int x, float4& v, float& el, float& er) {
        const float* row = img + (long long)x * IMG_W;
        v  = *(const float4*)(row + y4);
        el = row[yl];
        er = row[yr];
    };

    float4 u, c, d;
    float ul, ur, cl, cr, dl, dr;

    const int xu0 = (x0 > 0) ? x0 - 1 : 0;   // clamped; row 0 outputs are 0 anyway
    load_row(xu0, u, ul, ur);
    load_row(x0,  c, cl, cr);

    #pragma unroll
    for (int i = 0; i < ROWS_PER_THREAD; ++i) {
        const int x  = x0 + i;
        const int xd = (x < IMG_H - 1) ? x + 1 : IMG_H - 1;
        load_row(xd, d, dl, dr);

        const long long base = (long long)x * IMG_W + y4;
        const float4 th = *(const float4*)(theta + base);

        const float cv[6] = {cl, c.x, c.y, c.z, c.w, cr};
        const float uv[6] = {ul, u.x, u.y, u.z, u.w, ur};
        const float dv[6] = {dl, d.x, d.y, d.z, d.w, dr};
        const float tv[4] = {th.x, th.y, th.z, th.w};

        const bool row_interior = (x > 0) && (x < IMG_H - 1);
        float ov[4];

        #pragma unroll
        for (int j = 0; j < 4; ++j) {
            const float v = cv[j + 1];

            // ---- quantize angle exactly like the reference float32 path ----
            float deg = tv[j] * 57.29577951308232f;   // float32(180/pi)
            if (deg < 0.0f) deg += 180.0f;
            float q = rintf(deg / 45.0f) * 45.0f;     // true div + round-half-even
            if (q == 180.0f) q = 0.0f;

            float a, b;
            if (q == 0.0f) {          // (x, y+-1)
                a = cv[j + 2]; b = cv[j];
            } else if (q == 45.0f) {  // (x+1, y+1), (x-1, y-1)
                a = dv[j + 2]; b = uv[j];
            } else if (q == 90.0f) {  // (x+-1, y)
                a = dv[j + 1]; b = uv[j + 1];
            } else {                  // 135 branch (incl. any other q)
                a = dv[j]; b = uv[j + 2];
            }

            const int y = y4 + j;
            const bool interior = row_interior && (y > 0) && (y < IMG_W - 1);
            ov[j] = ((v >= a) && (v >= b) && interior) ? v : 0.0f;
        }

        float4 o;
        o.x = ov[0]; o.y = ov[1]; o.z = ov[2]; o.w = ov[3];
        *(float4*)(out + base) = o;

        // shift the row window down
        u = c; ul = cl; ur = cr;
        c = d; cl = dl; cr = dr;
    }
}

extern "C" void kernel_launch(void* const* d_in, const int* in_sizes, int n_in,
                              void* d_out, int out_size, void* d_ws, size_t ws_size,
                              hipStream_t stream) {
    const float* img   = (const float*)d_in[0];
    const float* theta = (const float*)d_in[1];
    float* out = (float*)d_out;

    const int total_threads = (IMG_H / ROWS_PER_THREAD) * (IMG_W / 4); // 512 * 1024
    const int block = 256;
    const int grid = total_threads / block;                            // 2048
    nms_kernel<<<grid, block, 0, stream>>>(img, theta, out);
}

// Round 3
// 170.412 us; speedup vs baseline: 1.0305x; 1.0305x over previous
//
#include <hip/hip_runtime.h>
#include <math.h>

#define IMG_H 4096
#define IMG_W 4096
#define RPT 4   // rows per thread

// Per-pixel NMS: quantize angle exactly like the reference float32 path, pick
// the two neighbors branchlessly, emit img if local-max & interior.
// All scalars — NO local arrays (arrays were being demoted to scratch and the
// resulting private-memory traffic (~1.2 GB) was the real bottleneck in r1/r2).
__device__ __forceinline__ float nms_px(float t, bool interior,
                                        float uL, float uC, float uR,
                                        float cL, float cC, float cR,
                                        float dL, float dC, float dR) {
    float deg = t * 57.29577951308232f;        // float32(180/pi)
    deg = (deg < 0.0f) ? deg + 180.0f : deg;
    float q = rintf(deg / 45.0f) * 45.0f;      // true IEEE div + round-half-even
    // q==180 folds to the 0-branch; any other q (negative, >=225) -> 135 branch,
    // identical to the reference's nested where-chain.
    const bool is0  = (q == 0.0f) || (q == 180.0f);
    const bool is45 = (q == 45.0f);
    const bool is90 = (q == 90.0f);
    const float a = is0 ? cR : (is45 ? dR : (is90 ? dC : dL));
    const float b = is0 ? cL : (is45 ? uL : (is90 ? uC : uR));
    return ((cC >= a) && (cC >= b) && interior) ? cC : 0.0f;
}

__global__ __launch_bounds__(256) void nms_kernel(const float* __restrict__ img,
                                                  const float* __restrict__ theta,
                                                  float* __restrict__ out) {
    const int tid = blockIdx.x * blockDim.x + threadIdx.x;
    const int g  = tid >> 10;            // row-group; 1024 quad-cols per group
    const int y4 = (tid & 1023) << 2;    // starting column of the 4-px chunk
    const int x0 = g * RPT;

    const int yl = (y4 > 0)         ? y4 - 1 : 0;        // clamped; col-border px output 0
    const int yr = (y4 + 4 < IMG_W) ? y4 + 4 : IMG_W - 1;

    const bool col0_int = (y4 > 0);
    const bool col3_int = (y4 + 4 < IMG_W);

    float4 u, c, d;
    float ul, ur, cl, cr, dl, dr;

    {
        const int xu0 = (x0 > 0) ? x0 - 1 : 0;           // clamped; row 0 outputs 0
        const float* __restrict__ pr = img + (size_t)xu0 * IMG_W;
        u = *(const float4*)(pr + y4); ul = pr[yl]; ur = pr[yr];
    }
    {
        const float* __restrict__ pr = img + (size_t)x0 * IMG_W;
        c = *(const float4*)(pr + y4); cl = pr[yl]; cr = pr[yr];
    }

    #pragma unroll
    for (int i = 0; i < RPT; ++i) {
        const int x  = x0 + i;
        const int xd = (x < IMG_H - 1) ? x + 1 : IMG_H - 1;
        {
            const float* __restrict__ pr = img + (size_t)xd * IMG_W;
            d = *(const float4*)(pr + y4); dl = pr[yl]; dr = pr[yr];
        }

        const size_t base = (size_t)x * IMG_W + y4;
        const float4 th = *(const float4*)(theta + base);

        const bool row_int = (x > 0) && (x < IMG_H - 1);

        float4 o;
        o.x = nms_px(th.x, row_int && col0_int, ul,  u.x, u.y,  cl,  c.x, c.y,  dl,  d.x, d.y);
        o.y = nms_px(th.y, row_int,             u.x, u.y, u.z,  c.x, c.y, c.z,  d.x, d.y, d.z);
        o.z = nms_px(th.z, row_int,             u.y, u.z, u.w,  c.y, c.z, c.w,  d.y, d.z, d.w);
        o.w = nms_px(th.w, row_int && col3_int, u.z, u.w, ur,   c.z, c.w, cr,   d.z, d.w, dr);

        *(float4*)(out + base) = o;

        // slide the 3-row window down
        u = c; ul = cl; ur = cr;
        c = d; cl = dl; cr = dr;
    }
}

extern "C" void kernel_launch(void* const* d_in, const int* in_sizes, int n_in,
                              void* d_out, int out_size, void* d_ws, size_t ws_size,
                              hipStream_t stream) {
    const float* img   = (const float*)d_in[0];
    const float* theta = (const float*)d_in[1];
    float* out = (float*)d_out;

    const int total_threads = (IMG_H / RPT) * (IMG_W / 4);  // 1024 * 1024
    const int block = 256;
    const int grid = total_threads / block;                  // 4096
    nms_kernel<<<grid, block, 0, stream>>>(img, theta, out);
}